// Round 1
// baseline (635.321 us; speedup 1.0000x reference)
//
#include <hip/hip_runtime.h>

// ---------------------------------------------------------------------------
// 2-layer GCN on MI355X.
//   h  = relu( Dinv (A+I) Dinv (z @ W1) + b1 )
//   out =      Dinv (A+I) Dinv (h @ W2) + b2
// deg[i] = (#edges with dst==i) + 1 (self-loop);  dinv = rsqrt(deg)
// Strategy: build CSR-by-dst on device (no f32 atomics), gather-aggregate
// one wave per node with coalesced float4 feature loads.
// ---------------------------------------------------------------------------

#define N_NODES 50000
#define N_EDGES 800000
#define D_IN    256
#define D_HID   256
#define D_OUT   128

// ---------------- CSR build ----------------

__global__ void degree_kernel(const int* __restrict__ dst, int* __restrict__ cnt, int n_edges) {
    int i = blockIdx.x * blockDim.x + threadIdx.x;
    if (i < n_edges) atomicAdd(&cnt[dst[i]], 1);
}

__global__ void dinv_kernel(const int* __restrict__ cnt, float* __restrict__ dinv, int n) {
    int i = blockIdx.x * blockDim.x + threadIdx.x;
    if (i < n) dinv[i] = rsqrtf((float)(cnt[i] + 1));   // +1 self-loop; always >= 1
}

// Single-block exclusive scan of cnt[0..n) -> row_ptr / cursor; row_ptr[n]=total.
__global__ __launch_bounds__(1024) void scan_kernel(const int* __restrict__ cnt,
                                                    int* __restrict__ row_ptr,
                                                    int* __restrict__ cursor, int n) {
    const int T = 1024;
    int t = threadIdx.x;
    int chunk = (n + T - 1) / T;
    int begin = t * chunk;
    int end = begin + chunk; if (end > n) end = n;

    int s = 0;
    for (int i = begin; i < end; ++i) s += cnt[i];

    // wave-level inclusive scan (wave = 64)
    int lane = t & 63, w = t >> 6;          // 16 waves
    int v = s;
    #pragma unroll
    for (int off = 1; off < 64; off <<= 1) {
        int u = __shfl_up(v, off, 64);
        if (lane >= off) v += u;
    }
    __shared__ int wsum[16];
    __shared__ int woff[16];
    if (lane == 63) wsum[w] = v;
    __syncthreads();
    if (t == 0) {
        int run = 0;
        #pragma unroll
        for (int i = 0; i < 16; ++i) { woff[i] = run; run += wsum[i]; }
        row_ptr[n] = run;
    }
    __syncthreads();

    int run = woff[w] + (v - s);            // exclusive prefix for this thread's chunk
    for (int i = begin; i < end; ++i) {
        row_ptr[i] = run;
        cursor[i]  = run;
        run += cnt[i];
    }
}

__global__ void fill_kernel(const int* __restrict__ src, const int* __restrict__ dst,
                            int* __restrict__ cursor, int* __restrict__ col, int n_edges) {
    int i = blockIdx.x * blockDim.x + threadIdx.x;
    if (i < n_edges) {
        int d = dst[i];
        int pos = atomicAdd(&cursor[d], 1);
        col[pos] = src[i];
    }
}

// ---------------- GEMM: C[M x N] = A[M x 256] * B[256 x N] ----------------
// BM=64, BN=64, BK=16; 256 threads; 4x4 micro-tile per thread.

template <int N>
__global__ __launch_bounds__(256) void gemm_kernel(const float* __restrict__ A,
                                                   const float* __restrict__ B,
                                                   float* __restrict__ C, int M) {
    const int K = 256;
    __shared__ float As[16][68];   // [k][m], stride 68 keeps float4 alignment, 2-way max bank alias
    __shared__ float Bs[16][68];   // [k][n]

    int m0 = blockIdx.x * 64;
    int n0 = blockIdx.y * 64;
    int t  = threadIdx.x;

    int tm = (t >> 4) * 4;        // 0..60
    int tn = (t & 15) * 4;        // 0..60

    int a_m = t >> 2;             // 0..63
    int a_k = (t & 3) * 4;        // 0..12
    int b_k = t >> 4;             // 0..15
    int b_n = (t & 15) * 4;       // 0..60

    float acc[4][4] = {};

    for (int k0 = 0; k0 < K; k0 += 16) {
        int gm = m0 + a_m;
        float4 av = make_float4(0.f, 0.f, 0.f, 0.f);
        if (gm < M) av = *(const float4*)(A + (size_t)gm * K + k0 + a_k);
        As[a_k + 0][a_m] = av.x;
        As[a_k + 1][a_m] = av.y;
        As[a_k + 2][a_m] = av.z;
        As[a_k + 3][a_m] = av.w;

        float4 bv = *(const float4*)(B + (size_t)(k0 + b_k) * N + n0 + b_n);
        *(float4*)&Bs[b_k][b_n] = bv;

        __syncthreads();

        #pragma unroll
        for (int k = 0; k < 16; ++k) {
            float4 a4 = *(const float4*)&As[k][tm];
            float4 b4 = *(const float4*)&Bs[k][tn];
            float ar[4] = {a4.x, a4.y, a4.z, a4.w};
            float br[4] = {b4.x, b4.y, b4.z, b4.w};
            #pragma unroll
            for (int i = 0; i < 4; ++i)
                #pragma unroll
                for (int j = 0; j < 4; ++j)
                    acc[i][j] = fmaf(ar[i], br[j], acc[i][j]);
        }
        __syncthreads();
    }

    #pragma unroll
    for (int i = 0; i < 4; ++i) {
        int gm = m0 + tm + i;
        if (gm < M) {
            float4 v = make_float4(acc[i][0], acc[i][1], acc[i][2], acc[i][3]);
            *(float4*)(C + (size_t)gm * N + n0 + tn) = v;
        }
    }
}

// ---------------- Aggregation: one wave per node, gather over CSR ----------------

template <int D, bool RELU>
__global__ __launch_bounds__(256) void aggregate_kernel(const float* __restrict__ x,
                                                        const int* __restrict__ row_ptr,
                                                        const int* __restrict__ col,
                                                        const float* __restrict__ dinv,
                                                        const float* __restrict__ bias,
                                                        float* __restrict__ out, int n_nodes) {
    constexpr int VPL = D / 64;   // floats per lane: 4 (D=256) or 2 (D=128)
    int wave = (blockIdx.x * blockDim.x + threadIdx.x) >> 6;
    int lane = threadIdx.x & 63;
    if (wave >= n_nodes) return;
    const int node = wave;
    const int c0 = lane * VPL;

    float di = dinv[node];
    float acc[VPL];

    {   // self-loop term: x[node] * dinv[node]^2
        float w = di * di;
        const float* xs = x + (size_t)node * D + c0;
        if constexpr (VPL == 4) {
            float4 v = *(const float4*)xs;
            acc[0] = v.x * w; acc[1] = v.y * w; acc[2] = v.z * w; acc[3] = v.w * w;
        } else {
            float2 v = *(const float2*)xs;
            acc[0] = v.x * w; acc[1] = v.y * w;
        }
    }

    int e0 = row_ptr[node], e1 = row_ptr[node + 1];
    for (int e = e0; e < e1; ++e) {
        int s = col[e];
        float w = dinv[s] * di;
        const float* xs = x + (size_t)s * D + c0;
        if constexpr (VPL == 4) {
            float4 v = *(const float4*)xs;
            acc[0] = fmaf(v.x, w, acc[0]);
            acc[1] = fmaf(v.y, w, acc[1]);
            acc[2] = fmaf(v.z, w, acc[2]);
            acc[3] = fmaf(v.w, w, acc[3]);
        } else {
            float2 v = *(const float2*)xs;
            acc[0] = fmaf(v.x, w, acc[0]);
            acc[1] = fmaf(v.y, w, acc[1]);
        }
    }

    float* op = out + (size_t)node * D + c0;
    #pragma unroll
    for (int j = 0; j < VPL; ++j) {
        float v = acc[j] + bias[c0 + j];
        if (RELU) v = fmaxf(v, 0.0f);
        op[j] = v;
    }
}

// ---------------- launcher ----------------

extern "C" void kernel_launch(void* const* d_in, const int* in_sizes, int n_in,
                              void* d_out, int out_size, void* d_ws, size_t ws_size,
                              hipStream_t stream) {
    const float* z  = (const float*)d_in[0];
    const int*   ei = (const int*)d_in[1];
    const float* W1 = (const float*)d_in[2];
    const float* b1 = (const float*)d_in[3];
    const float* W2 = (const float*)d_in[4];
    const float* b2 = (const float*)d_in[5];
    float* out = (float*)d_out;

    const int Nn = N_NODES, E = N_EDGES;
    const int* srcp = ei;
    const int* dstp = ei + E;

    // workspace carve-up
    char* ws = (char*)d_ws;
    size_t off = 0;
    auto alloc = [&](size_t bytes) -> char* {
        char* p = ws + off;
        off += (bytes + 511) & ~(size_t)511;
        return p;
    };
    float* x1      = (float*)alloc((size_t)Nn * D_HID * 4);  // z @ W1
    float* h       = (float*)alloc((size_t)Nn * D_HID * 4);  // relu(agg(x1)+b1)
    int*   cnt     = (int*)  alloc((size_t)Nn * 4);
    float* dinv    = (float*)alloc((size_t)Nn * 4);
    int*   row_ptr = (int*)  alloc((size_t)(Nn + 1) * 4);
    int*   cursor  = (int*)  alloc((size_t)Nn * 4);
    int*   col     = (int*)  alloc((size_t)E * 4);
    float* h2      = x1;  // reuse x1 buffer for h @ W2 (only 25.6 MB needed)

    // ---- CSR build ----
    hipMemsetAsync(cnt, 0, (size_t)Nn * 4, stream);
    degree_kernel<<<(E + 255) / 256, 256, 0, stream>>>(dstp, cnt, E);
    dinv_kernel<<<(Nn + 255) / 256, 256, 0, stream>>>(cnt, dinv, Nn);
    scan_kernel<<<1, 1024, 0, stream>>>(cnt, row_ptr, cursor, Nn);
    fill_kernel<<<(E + 255) / 256, 256, 0, stream>>>(srcp, dstp, cursor, col, E);

    // ---- layer 1 ----
    {
        dim3 grid((Nn + 63) / 64, D_HID / 64);
        gemm_kernel<D_HID><<<grid, 256, 0, stream>>>(z, W1, x1, Nn);
    }
    {
        int blocks = (Nn * 64 + 255) / 256;   // one wave per node, 4 waves/block
        aggregate_kernel<D_HID, true><<<blocks, 256, 0, stream>>>(x1, row_ptr, col, dinv, b1, h, Nn);
    }

    // ---- layer 2 ----
    {
        dim3 grid((Nn + 63) / 64, D_OUT / 64);
        gemm_kernel<D_OUT><<<grid, 256, 0, stream>>>(h, W2, h2, Nn);
    }
    {
        int blocks = (Nn * 64 + 255) / 256;
        aggregate_kernel<D_OUT, false><<<blocks, 256, 0, stream>>>(h2, row_ptr, col, dinv, b2, out, Nn);
    }
}

// Round 2
// 504.152 us; speedup vs baseline: 1.2602x; 1.2602x over previous
//
#include <hip/hip_runtime.h>

// ---------------------------------------------------------------------------
// 2-layer GCN on MI355X (all-f32).
//   h   = relu( Dinv (A+I) Dinv (z @ W1) + b1 )
//   out =       Dinv (A+I) Dinv (h @ W2) + b2
// R2: 128x128x16 f32 GEMM (8x8/thread), 3-kernel coalesced scan, per-edge
// weights precomputed, aggregate gather unrolled x4.
// ---------------------------------------------------------------------------

#define N_NODES 50000
#define N_EDGES 800000
#define D_IN    256
#define D_HID   256
#define D_OUT   128

// ---------------- CSR build ----------------

__global__ void degree_kernel(const int* __restrict__ dst, int* __restrict__ cnt, int n_edges) {
    int i = blockIdx.x * blockDim.x + threadIdx.x;
    if (i < n_edges) atomicAdd(&cnt[dst[i]], 1);
}

__global__ void dinv_kernel(const int* __restrict__ cnt, float* __restrict__ dinv, int n) {
    int i = blockIdx.x * blockDim.x + threadIdx.x;
    if (i < n) dinv[i] = rsqrtf((float)(cnt[i] + 1));   // +1 self-loop; always >= 1
}

// --- 3-kernel coalesced exclusive scan of cnt[0..n) ---

__global__ __launch_bounds__(256) void block_sum_kernel(const int* __restrict__ cnt,
                                                        int* __restrict__ bsum, int n) {
    int b = blockIdx.x, t = threadIdx.x;
    int i = b * 256 + t;
    int v = (i < n) ? cnt[i] : 0;
    #pragma unroll
    for (int off = 32; off >= 1; off >>= 1) v += __shfl_down(v, off, 64);
    __shared__ int ws[4];
    if ((t & 63) == 0) ws[t >> 6] = v;
    __syncthreads();
    if (t == 0) bsum[b] = ws[0] + ws[1] + ws[2] + ws[3];
}

// nb <= 256 required (N_NODES=50000 -> nb=196)
__global__ __launch_bounds__(256) void scan_partials_kernel(const int* __restrict__ bsum,
                                                            int* __restrict__ boff,
                                                            int* __restrict__ row_ptr,
                                                            int nb, int n) {
    int t = threadIdx.x;
    int v = (t < nb) ? bsum[t] : 0;
    int lane = t & 63, w = t >> 6;
    int x = v;
    #pragma unroll
    for (int off = 1; off < 64; off <<= 1) {
        int u = __shfl_up(x, off, 64);
        if (lane >= off) x += u;
    }
    __shared__ int ws[4];
    if (lane == 63) ws[w] = x;
    __syncthreads();
    int base = 0;
    for (int i = 0; i < w; ++i) base += ws[i];
    int incl = base + x;
    if (t < nb) boff[t] = incl - v;           // exclusive prefix of block sums
    if (t == 255) row_ptr[n] = incl;          // grand total
}

__global__ __launch_bounds__(256) void scan_write_kernel(const int* __restrict__ cnt,
                                                         const int* __restrict__ boff,
                                                         int* __restrict__ row_ptr,
                                                         int* __restrict__ cursor, int n) {
    int b = blockIdx.x, t = threadIdx.x;
    int i = b * 256 + t;
    int v = (i < n) ? cnt[i] : 0;
    int lane = t & 63, w = t >> 6;
    int x = v;
    #pragma unroll
    for (int off = 1; off < 64; off <<= 1) {
        int u = __shfl_up(x, off, 64);
        if (lane >= off) x += u;
    }
    __shared__ int ws[4];
    if (lane == 63) ws[w] = x;
    __syncthreads();
    int base = boff[b];
    for (int i2 = 0; i2 < w; ++i2) base += ws[i2];
    int excl = base + (x - v);
    if (i < n) { row_ptr[i] = excl; cursor[i] = excl; }
}

// fill: also precompute per-edge weight dinv[src]*dinv[dst]
__global__ void fill_kernel(const int* __restrict__ src, const int* __restrict__ dst,
                            const float* __restrict__ dinv,
                            int* __restrict__ cursor, int* __restrict__ col,
                            float* __restrict__ ew, int n_edges) {
    int i = blockIdx.x * blockDim.x + threadIdx.x;
    if (i < n_edges) {
        int d = dst[i];
        int s = src[i];
        int pos = atomicAdd(&cursor[d], 1);
        col[pos] = s;
        ew[pos]  = dinv[s] * dinv[d];
    }
}

// ---------------- GEMM: C[M x N] = A[M x 256] * B[256 x N] ----------------
// BM=128, BN=128, BK=16; 256 threads; 8x8 micro-tile per thread.

template <int N>
__global__ __launch_bounds__(256, 2) void gemm_kernel(const float* __restrict__ A,
                                                      const float* __restrict__ B,
                                                      float* __restrict__ C, int M) {
    const int K = 256;
    constexpr int LDP = 132;            // 128 + 4 pad
    __shared__ float As[16][LDP];       // [k][m] (transposed)
    __shared__ float Bs[16][LDP];       // [k][n]

    int m0 = blockIdx.x * 128;
    int n0 = blockIdx.y * 128;
    int t  = threadIdx.x;

    int tm = (t >> 4) * 8;              // 0..120
    int tn = (t & 15) * 8;              // 0..120

    int a_m = t >> 1;                   // 0..127
    int a_k = (t & 1) * 8;              // 0 or 8
    int b_k = t >> 4;                   // 0..15
    int b_n = (t & 15) * 8;             // 0..120

    float acc[8][8] = {};

    for (int k0 = 0; k0 < K; k0 += 16) {
        int gm = m0 + a_m;
        float4 av0 = make_float4(0.f, 0.f, 0.f, 0.f);
        float4 av1 = av0;
        if (gm < M) {
            const float* ap = A + (size_t)gm * K + k0 + a_k;
            av0 = *(const float4*)(ap);
            av1 = *(const float4*)(ap + 4);
        }
        As[a_k + 0][a_m] = av0.x;
        As[a_k + 1][a_m] = av0.y;
        As[a_k + 2][a_m] = av0.z;
        As[a_k + 3][a_m] = av0.w;
        As[a_k + 4][a_m] = av1.x;
        As[a_k + 5][a_m] = av1.y;
        As[a_k + 6][a_m] = av1.z;
        As[a_k + 7][a_m] = av1.w;

        const float* bp = B + (size_t)(k0 + b_k) * N + n0 + b_n;
        *(float4*)&Bs[b_k][b_n]     = *(const float4*)(bp);
        *(float4*)&Bs[b_k][b_n + 4] = *(const float4*)(bp + 4);

        __syncthreads();

        #pragma unroll
        for (int k = 0; k < 16; ++k) {
            float ar[8], br[8];
            *(float4*)&ar[0] = *(const float4*)&As[k][tm];
            *(float4*)&ar[4] = *(const float4*)&As[k][tm + 4];
            *(float4*)&br[0] = *(const float4*)&Bs[k][tn];
            *(float4*)&br[4] = *(const float4*)&Bs[k][tn + 4];
            #pragma unroll
            for (int i = 0; i < 8; ++i)
                #pragma unroll
                for (int j = 0; j < 8; ++j)
                    acc[i][j] = fmaf(ar[i], br[j], acc[i][j]);
        }
        __syncthreads();
    }

    #pragma unroll
    for (int i = 0; i < 8; ++i) {
        int gm = m0 + tm + i;
        if (gm < M) {
            float* cp = C + (size_t)gm * N + n0 + tn;
            *(float4*)(cp)     = make_float4(acc[i][0], acc[i][1], acc[i][2], acc[i][3]);
            *(float4*)(cp + 4) = make_float4(acc[i][4], acc[i][5], acc[i][6], acc[i][7]);
        }
    }
}

// ---------------- Aggregation: one wave per node, gather over CSR ----------------

template <int D, bool RELU>
__global__ __launch_bounds__(256) void aggregate_kernel(const float* __restrict__ x,
                                                        const int* __restrict__ row_ptr,
                                                        const int* __restrict__ col,
                                                        const float* __restrict__ ew,
                                                        const float* __restrict__ dinv,
                                                        const float* __restrict__ bias,
                                                        float* __restrict__ out, int n_nodes) {
    constexpr int VPL = D / 64;   // floats per lane: 4 (D=256) or 2 (D=128)
    int wave = (blockIdx.x * blockDim.x + threadIdx.x) >> 6;
    int lane = threadIdx.x & 63;
    if (wave >= n_nodes) return;
    const int node = wave;
    const int c0 = lane * VPL;

    float di = dinv[node];
    float acc[4][VPL] = {};

    {   // self-loop term: x[node] * dinv[node]^2
        float w = di * di;
        const float* xs = x + (size_t)node * D + c0;
        if constexpr (VPL == 4) {
            float4 v = *(const float4*)xs;
            acc[0][0] = v.x * w; acc[0][1] = v.y * w; acc[0][2] = v.z * w; acc[0][3] = v.w * w;
        } else {
            float2 v = *(const float2*)xs;
            acc[0][0] = v.x * w; acc[0][1] = v.y * w;
        }
    }

    int e0 = row_ptr[node], e1 = row_ptr[node + 1];
    int e = e0;
    for (; e + 4 <= e1; e += 4) {
        #pragma unroll
        for (int u = 0; u < 4; ++u) {
            int s  = col[e + u];
            float w = ew[e + u];
            const float* xs = x + (size_t)s * D + c0;
            if constexpr (VPL == 4) {
                float4 v = *(const float4*)xs;
                acc[u][0] = fmaf(v.x, w, acc[u][0]);
                acc[u][1] = fmaf(v.y, w, acc[u][1]);
                acc[u][2] = fmaf(v.z, w, acc[u][2]);
                acc[u][3] = fmaf(v.w, w, acc[u][3]);
            } else {
                float2 v = *(const float2*)xs;
                acc[u][0] = fmaf(v.x, w, acc[u][0]);
                acc[u][1] = fmaf(v.y, w, acc[u][1]);
            }
        }
    }
    for (; e < e1; ++e) {
        int s  = col[e];
        float w = ew[e];
        const float* xs = x + (size_t)s * D + c0;
        if constexpr (VPL == 4) {
            float4 v = *(const float4*)xs;
            acc[0][0] = fmaf(v.x, w, acc[0][0]);
            acc[0][1] = fmaf(v.y, w, acc[0][1]);
            acc[0][2] = fmaf(v.z, w, acc[0][2]);
            acc[0][3] = fmaf(v.w, w, acc[0][3]);
        } else {
            float2 v = *(const float2*)xs;
            acc[0][0] = fmaf(v.x, w, acc[0][0]);
            acc[0][1] = fmaf(v.y, w, acc[0][1]);
        }
    }

    float* op = out + (size_t)node * D + c0;
    #pragma unroll
    for (int j = 0; j < VPL; ++j) {
        float v = acc[0][j] + acc[1][j] + acc[2][j] + acc[3][j] + bias[c0 + j];
        if (RELU) v = fmaxf(v, 0.0f);
        op[j] = v;
    }
}

// ---------------- launcher ----------------

extern "C" void kernel_launch(void* const* d_in, const int* in_sizes, int n_in,
                              void* d_out, int out_size, void* d_ws, size_t ws_size,
                              hipStream_t stream) {
    const float* z  = (const float*)d_in[0];
    const int*   ei = (const int*)d_in[1];
    const float* W1 = (const float*)d_in[2];
    const float* b1 = (const float*)d_in[3];
    const float* W2 = (const float*)d_in[4];
    const float* b2 = (const float*)d_in[5];
    float* out = (float*)d_out;

    const int Nn = N_NODES, E = N_EDGES;
    const int* srcp = ei;
    const int* dstp = ei + E;

    // workspace carve-up
    char* ws = (char*)d_ws;
    size_t off = 0;
    auto alloc = [&](size_t bytes) -> char* {
        char* p = ws + off;
        off += (bytes + 511) & ~(size_t)511;
        return p;
    };
    float* x1      = (float*)alloc((size_t)Nn * D_HID * 4);  // z @ W1
    float* h       = (float*)alloc((size_t)Nn * D_HID * 4);  // relu(agg(x1)+b1)
    int*   cnt     = (int*)  alloc((size_t)Nn * 4);
    float* dinv    = (float*)alloc((size_t)Nn * 4);
    int*   row_ptr = (int*)  alloc((size_t)(Nn + 1) * 4);
    int*   cursor  = (int*)  alloc((size_t)Nn * 4);
    int*   col     = (int*)  alloc((size_t)E * 4);
    float* ew      = (float*)alloc((size_t)E * 4);
    int*   bsum    = (int*)  alloc(256 * 4);
    int*   boff    = (int*)  alloc(256 * 4);
    float* h2      = x1;  // reuse x1 buffer for h @ W2 (only 25.6 MB needed)

    const int nb = (Nn + 255) / 256;   // 196 scan blocks

    // ---- CSR build ----
    hipMemsetAsync(cnt, 0, (size_t)Nn * 4, stream);
    degree_kernel<<<(E + 255) / 256, 256, 0, stream>>>(dstp, cnt, E);
    dinv_kernel<<<(Nn + 255) / 256, 256, 0, stream>>>(cnt, dinv, Nn);
    block_sum_kernel<<<nb, 256, 0, stream>>>(cnt, bsum, Nn);
    scan_partials_kernel<<<1, 256, 0, stream>>>(bsum, boff, row_ptr, nb, Nn);
    scan_write_kernel<<<nb, 256, 0, stream>>>(cnt, boff, row_ptr, cursor, Nn);
    fill_kernel<<<(E + 255) / 256, 256, 0, stream>>>(srcp, dstp, dinv, cursor, col, ew, E);

    // ---- layer 1 ----
    {
        dim3 grid((Nn + 127) / 128, D_HID / 128);
        gemm_kernel<D_HID><<<grid, 256, 0, stream>>>(z, W1, x1, Nn);
    }
    {
        int blocks = (Nn * 64 + 255) / 256;   // one wave per node
        aggregate_kernel<D_HID, true><<<blocks, 256, 0, stream>>>(x1, row_ptr, col, ew, dinv, b1, h, Nn);
    }

    // ---- layer 2 ----
    {
        dim3 grid((Nn + 127) / 128, D_OUT / 128);
        gemm_kernel<D_OUT><<<grid, 256, 0, stream>>>(h, W2, h2, Nn);
    }
    {
        int blocks = (Nn * 64 + 255) / 256;
        aggregate_kernel<D_OUT, false><<<blocks, 256, 0, stream>>>(h2, row_ptr, col, ew, dinv, b2, out, Nn);
    }
}

// Round 3
// 453.546 us; speedup vs baseline: 1.4008x; 1.1116x over previous
//
#include <hip/hip_runtime.h>

// ---------------------------------------------------------------------------
// 2-layer GCN on MI355X.
//   h   = relu( Dinv (A+I) Dinv (z @ W1) + b1 )
//   out =       Dinv (A+I) Dinv (h @ W2) + b2
// R3: GEMM outputs stored bf16 (RNE); aggregation gathers packed bf16
// (halves the BW-bound gather traffic), accumulates f32. GEMMs still f32.
// ---------------------------------------------------------------------------

#define N_NODES 50000
#define N_EDGES 800000
#define D_IN    256
#define D_HID   256
#define D_OUT   128

typedef unsigned int uint32;
typedef unsigned short ushort16;

__device__ __forceinline__ ushort16 f2bf_rne(float f) {
    union { float f; uint32 u; } c; c.f = f;
    uint32 u = c.u;
    u += 0x7FFFu + ((u >> 16) & 1u);
    return (ushort16)(u >> 16);
}
__device__ __forceinline__ float bf_lo(uint32 p) {   // low 16 bits -> float
    union { uint32 u; float f; } c; c.u = p << 16; return c.f;
}
__device__ __forceinline__ float bf_hi(uint32 p) {   // high 16 bits -> float
    union { uint32 u; float f; } c; c.u = p & 0xFFFF0000u; return c.f;
}

// ---------------- CSR build ----------------

__global__ void degree_kernel(const int* __restrict__ dst, int* __restrict__ cnt, int n_edges) {
    int i = blockIdx.x * blockDim.x + threadIdx.x;
    if (i < n_edges) atomicAdd(&cnt[dst[i]], 1);
}

__global__ void dinv_kernel(const int* __restrict__ cnt, float* __restrict__ dinv, int n) {
    int i = blockIdx.x * blockDim.x + threadIdx.x;
    if (i < n) dinv[i] = rsqrtf((float)(cnt[i] + 1));   // +1 self-loop; always >= 1
}

__global__ __launch_bounds__(256) void block_sum_kernel(const int* __restrict__ cnt,
                                                        int* __restrict__ bsum, int n) {
    int b = blockIdx.x, t = threadIdx.x;
    int i = b * 256 + t;
    int v = (i < n) ? cnt[i] : 0;
    #pragma unroll
    for (int off = 32; off >= 1; off >>= 1) v += __shfl_down(v, off, 64);
    __shared__ int ws[4];
    if ((t & 63) == 0) ws[t >> 6] = v;
    __syncthreads();
    if (t == 0) bsum[b] = ws[0] + ws[1] + ws[2] + ws[3];
}

// nb <= 256 required (N_NODES=50000 -> nb=196)
__global__ __launch_bounds__(256) void scan_partials_kernel(const int* __restrict__ bsum,
                                                            int* __restrict__ boff,
                                                            int* __restrict__ row_ptr,
                                                            int nb, int n) {
    int t = threadIdx.x;
    int v = (t < nb) ? bsum[t] : 0;
    int lane = t & 63, w = t >> 6;
    int x = v;
    #pragma unroll
    for (int off = 1; off < 64; off <<= 1) {
        int u = __shfl_up(x, off, 64);
        if (lane >= off) x += u;
    }
    __shared__ int ws[4];
    if (lane == 63) ws[w] = x;
    __syncthreads();
    int base = 0;
    for (int i = 0; i < w; ++i) base += ws[i];
    int incl = base + x;
    if (t < nb) boff[t] = incl - v;
    if (t == 255) row_ptr[n] = incl;
}

__global__ __launch_bounds__(256) void scan_write_kernel(const int* __restrict__ cnt,
                                                         const int* __restrict__ boff,
                                                         int* __restrict__ row_ptr,
                                                         int* __restrict__ cursor, int n) {
    int b = blockIdx.x, t = threadIdx.x;
    int i = b * 256 + t;
    int v = (i < n) ? cnt[i] : 0;
    int lane = t & 63, w = t >> 6;
    int x = v;
    #pragma unroll
    for (int off = 1; off < 64; off <<= 1) {
        int u = __shfl_up(x, off, 64);
        if (lane >= off) x += u;
    }
    __shared__ int ws[4];
    if (lane == 63) ws[w] = x;
    __syncthreads();
    int base = boff[b];
    for (int i2 = 0; i2 < w; ++i2) base += ws[i2];
    int excl = base + (x - v);
    if (i < n) { row_ptr[i] = excl; cursor[i] = excl; }
}

__global__ void fill_kernel(const int* __restrict__ src, const int* __restrict__ dst,
                            const float* __restrict__ dinv,
                            int* __restrict__ cursor, int* __restrict__ col,
                            float* __restrict__ ew, int n_edges) {
    int i = blockIdx.x * blockDim.x + threadIdx.x;
    if (i < n_edges) {
        int d = dst[i];
        int s = src[i];
        int pos = atomicAdd(&cursor[d], 1);
        col[pos] = s;
        ew[pos]  = dinv[s] * dinv[d];
    }
}

// ---------------- GEMM: C[M x N] = A[M x 256] * B[256 x N], C stored bf16 ----------------
// BM=128, BN=128, BK=16; 256 threads; 8x8 micro-tile per thread.

template <int N>
__global__ __launch_bounds__(256, 2) void gemm_kernel(const float* __restrict__ A,
                                                      const float* __restrict__ B,
                                                      ushort16* __restrict__ C, int M) {
    const int K = 256;
    constexpr int LDP = 132;
    __shared__ float As[16][LDP];       // [k][m]
    __shared__ float Bs[16][LDP];       // [k][n]

    int m0 = blockIdx.x * 128;
    int n0 = blockIdx.y * 128;
    int t  = threadIdx.x;

    int tm = (t >> 4) * 8;
    int tn = (t & 15) * 8;

    int a_m = t >> 1;
    int a_k = (t & 1) * 8;
    int b_k = t >> 4;
    int b_n = (t & 15) * 8;

    float acc[8][8] = {};

    for (int k0 = 0; k0 < K; k0 += 16) {
        int gm = m0 + a_m;
        float4 av0 = make_float4(0.f, 0.f, 0.f, 0.f);
        float4 av1 = av0;
        if (gm < M) {
            const float* ap = A + (size_t)gm * K + k0 + a_k;
            av0 = *(const float4*)(ap);
            av1 = *(const float4*)(ap + 4);
        }
        As[a_k + 0][a_m] = av0.x;
        As[a_k + 1][a_m] = av0.y;
        As[a_k + 2][a_m] = av0.z;
        As[a_k + 3][a_m] = av0.w;
        As[a_k + 4][a_m] = av1.x;
        As[a_k + 5][a_m] = av1.y;
        As[a_k + 6][a_m] = av1.z;
        As[a_k + 7][a_m] = av1.w;

        const float* bp = B + (size_t)(k0 + b_k) * N + n0 + b_n;
        *(float4*)&Bs[b_k][b_n]     = *(const float4*)(bp);
        *(float4*)&Bs[b_k][b_n + 4] = *(const float4*)(bp + 4);

        __syncthreads();

        #pragma unroll
        for (int k = 0; k < 16; ++k) {
            float ar[8], br[8];
            *(float4*)&ar[0] = *(const float4*)&As[k][tm];
            *(float4*)&ar[4] = *(const float4*)&As[k][tm + 4];
            *(float4*)&br[0] = *(const float4*)&Bs[k][tn];
            *(float4*)&br[4] = *(const float4*)&Bs[k][tn + 4];
            #pragma unroll
            for (int i = 0; i < 8; ++i)
                #pragma unroll
                for (int j = 0; j < 8; ++j)
                    acc[i][j] = fmaf(ar[i], br[j], acc[i][j]);
        }
        __syncthreads();
    }

    #pragma unroll
    for (int i = 0; i < 8; ++i) {
        int gm = m0 + tm + i;
        if (gm < M) {
            uint4 pk;
            pk.x = (uint32)f2bf_rne(acc[i][0]) | ((uint32)f2bf_rne(acc[i][1]) << 16);
            pk.y = (uint32)f2bf_rne(acc[i][2]) | ((uint32)f2bf_rne(acc[i][3]) << 16);
            pk.z = (uint32)f2bf_rne(acc[i][4]) | ((uint32)f2bf_rne(acc[i][5]) << 16);
            pk.w = (uint32)f2bf_rne(acc[i][6]) | ((uint32)f2bf_rne(acc[i][7]) << 16);
            *(uint4*)(C + (size_t)gm * N + n0 + tn) = pk;
        }
    }
}

// ---------------- Aggregation: one wave per node, bf16 gather over CSR ----------------

template <int D, bool RELU>
__global__ __launch_bounds__(256) void aggregate_kernel(const ushort16* __restrict__ x,
                                                        const int* __restrict__ row_ptr,
                                                        const int* __restrict__ col,
                                                        const float* __restrict__ ew,
                                                        const float* __restrict__ dinv,
                                                        const float* __restrict__ bias,
                                                        float* __restrict__ out, int n_nodes) {
    constexpr int VPL = D / 64;   // bf16s per lane: 4 (D=256) or 2 (D=128)
    int wave = (blockIdx.x * blockDim.x + threadIdx.x) >> 6;
    int lane = threadIdx.x & 63;
    if (wave >= n_nodes) return;
    const int node = wave;
    const int c0 = lane * VPL;

    float di = dinv[node];
    float acc[4][VPL] = {};

    {   // self-loop term: x[node] * dinv[node]^2
        float w = di * di;
        const ushort16* xs = x + (size_t)node * D + c0;
        if constexpr (VPL == 4) {
            uint2 p = *(const uint2*)xs;
            acc[0][0] = bf_lo(p.x) * w;
            acc[0][1] = bf_hi(p.x) * w;
            acc[0][2] = bf_lo(p.y) * w;
            acc[0][3] = bf_hi(p.y) * w;
        } else {
            uint32 p = *(const uint32*)xs;
            acc[0][0] = bf_lo(p) * w;
            acc[0][1] = bf_hi(p) * w;
        }
    }

    int e0 = row_ptr[node], e1 = row_ptr[node + 1];
    int e = e0;
    for (; e + 4 <= e1; e += 4) {
        #pragma unroll
        for (int u = 0; u < 4; ++u) {
            int s  = col[e + u];
            float w = ew[e + u];
            const ushort16* xs = x + (size_t)s * D + c0;
            if constexpr (VPL == 4) {
                uint2 p = *(const uint2*)xs;
                acc[u][0] = fmaf(bf_lo(p.x), w, acc[u][0]);
                acc[u][1] = fmaf(bf_hi(p.x), w, acc[u][1]);
                acc[u][2] = fmaf(bf_lo(p.y), w, acc[u][2]);
                acc[u][3] = fmaf(bf_hi(p.y), w, acc[u][3]);
            } else {
                uint32 p = *(const uint32*)xs;
                acc[u][0] = fmaf(bf_lo(p), w, acc[u][0]);
                acc[u][1] = fmaf(bf_hi(p), w, acc[u][1]);
            }
        }
    }
    for (; e < e1; ++e) {
        int s  = col[e];
        float w = ew[e];
        const ushort16* xs = x + (size_t)s * D + c0;
        if constexpr (VPL == 4) {
            uint2 p = *(const uint2*)xs;
            acc[0][0] = fmaf(bf_lo(p.x), w, acc[0][0]);
            acc[0][1] = fmaf(bf_hi(p.x), w, acc[0][1]);
            acc[0][2] = fmaf(bf_lo(p.y), w, acc[0][2]);
            acc[0][3] = fmaf(bf_hi(p.y), w, acc[0][3]);
        } else {
            uint32 p = *(const uint32*)xs;
            acc[0][0] = fmaf(bf_lo(p), w, acc[0][0]);
            acc[0][1] = fmaf(bf_hi(p), w, acc[0][1]);
        }
    }

    float* op = out + (size_t)node * D + c0;
    #pragma unroll
    for (int j = 0; j < VPL; ++j) {
        float v = acc[0][j] + acc[1][j] + acc[2][j] + acc[3][j] + bias[c0 + j];
        if (RELU) v = fmaxf(v, 0.0f);
        op[j] = v;
    }
}

// ---------------- launcher ----------------

extern "C" void kernel_launch(void* const* d_in, const int* in_sizes, int n_in,
                              void* d_out, int out_size, void* d_ws, size_t ws_size,
                              hipStream_t stream) {
    const float* z  = (const float*)d_in[0];
    const int*   ei = (const int*)d_in[1];
    const float* W1 = (const float*)d_in[2];
    const float* b1 = (const float*)d_in[3];
    const float* W2 = (const float*)d_in[4];
    const float* b2 = (const float*)d_in[5];
    float* out = (float*)d_out;

    const int Nn = N_NODES, E = N_EDGES;
    const int* srcp = ei;
    const int* dstp = ei + E;

    char* ws = (char*)d_ws;
    size_t off = 0;
    auto alloc = [&](size_t bytes) -> char* {
        char* p = ws + off;
        off += (bytes + 511) & ~(size_t)511;
        return p;
    };
    ushort16* x1b    = (ushort16*)alloc((size_t)Nn * D_HID * 2);  // z @ W1, bf16
    float*    h      = (float*)   alloc((size_t)Nn * D_HID * 4);  // relu(agg(x1)+b1), f32
    ushort16* h2b    = (ushort16*)alloc((size_t)Nn * D_OUT * 2);  // h @ W2, bf16
    int*      cnt    = (int*)     alloc((size_t)Nn * 4);
    float*    dinv   = (float*)   alloc((size_t)Nn * 4);
    int*      row_ptr= (int*)     alloc((size_t)(Nn + 1) * 4);
    int*      cursor = (int*)     alloc((size_t)Nn * 4);
    int*      col    = (int*)     alloc((size_t)E * 4);
    float*    ew     = (float*)   alloc((size_t)E * 4);
    int*      bsum   = (int*)     alloc(256 * 4);
    int*      boff   = (int*)     alloc(256 * 4);

    const int nb = (Nn + 255) / 256;

    // ---- CSR build ----
    hipMemsetAsync(cnt, 0, (size_t)Nn * 4, stream);
    degree_kernel<<<(E + 255) / 256, 256, 0, stream>>>(dstp, cnt, E);
    dinv_kernel<<<(Nn + 255) / 256, 256, 0, stream>>>(cnt, dinv, Nn);
    block_sum_kernel<<<nb, 256, 0, stream>>>(cnt, bsum, Nn);
    scan_partials_kernel<<<1, 256, 0, stream>>>(bsum, boff, row_ptr, nb, Nn);
    scan_write_kernel<<<nb, 256, 0, stream>>>(cnt, boff, row_ptr, cursor, Nn);
    fill_kernel<<<(E + 255) / 256, 256, 0, stream>>>(srcp, dstp, dinv, cursor, col, ew, E);

    // ---- layer 1 ----
    {
        dim3 grid((Nn + 127) / 128, D_HID / 128);
        gemm_kernel<D_HID><<<grid, 256, 0, stream>>>(z, W1, x1b, Nn);
    }
    {
        int blocks = (Nn * 64 + 255) / 256;
        aggregate_kernel<D_HID, true><<<blocks, 256, 0, stream>>>(x1b, row_ptr, col, ew, dinv, b1, h, Nn);
    }

    // ---- layer 2 ----
    {
        dim3 grid((Nn + 127) / 128, D_OUT / 128);
        gemm_kernel<D_OUT><<<grid, 256, 0, stream>>>(h, W2, h2b, Nn);
    }
    {
        int blocks = (Nn * 64 + 255) / 256;
        aggregate_kernel<D_OUT, false><<<blocks, 256, 0, stream>>>(h2b, row_ptr, col, ew, dinv, b2, out, Nn);
    }
}

// Round 4
// 320.985 us; speedup vs baseline: 1.9793x; 1.4130x over previous
//
#include <hip/hip_runtime.h>

// ---------------------------------------------------------------------------
// 2-layer GCN on MI355X.
//   h   = relu( Dinv (A+I) Dinv (z @ W1) + b1 )
//   out =       Dinv (A+I) Dinv (h @ W2) + b2
// R4: GEMMs moved to bf16 MFMA (mfma_f32_16x16x32_bf16, f32 accumulate),
// global_load_lds width-16 staging, pre-converted z_bf16 / W^T bf16.
// agg1 emits h as bf16 directly. Aggregation unchanged from R3.
// ---------------------------------------------------------------------------

#define N_NODES 50000
#define N_EDGES 800000
#define D_IN    256
#define D_HID   256
#define D_OUT   128

typedef unsigned int uint32;
typedef unsigned short u16;

typedef __attribute__((ext_vector_type(8))) short bf16x8;   // MFMA A/B frag (4 VGPR)
typedef __attribute__((ext_vector_type(4))) float f32x4;    // MFMA C/D frag

__device__ __forceinline__ u16 f2bf_rne(float f) {
    union { float f; uint32 u; } c; c.f = f;
    uint32 u = c.u;
    u += 0x7FFFu + ((u >> 16) & 1u);
    return (u16)(u >> 16);
}
__device__ __forceinline__ float bf_lo(uint32 p) {
    union { uint32 u; float f; } c; c.u = p << 16; return c.f;
}
__device__ __forceinline__ float bf_hi(uint32 p) {
    union { uint32 u; float f; } c; c.u = p & 0xFFFF0000u; return c.f;
}

// ---------------- conversion kernels ----------------

// f32 -> bf16, n multiple of 8
__global__ __launch_bounds__(256) void cvt_bf16_kernel(const float* __restrict__ in,
                                                       u16* __restrict__ out, int n) {
    int i = (blockIdx.x * blockDim.x + threadIdx.x) * 8;
    if (i < n) {
        float4 a = *(const float4*)(in + i);
        float4 b = *(const float4*)(in + i + 4);
        uint4 pk;
        pk.x = (uint32)f2bf_rne(a.x) | ((uint32)f2bf_rne(a.y) << 16);
        pk.y = (uint32)f2bf_rne(a.z) | ((uint32)f2bf_rne(a.w) << 16);
        pk.z = (uint32)f2bf_rne(b.x) | ((uint32)f2bf_rne(b.y) << 16);
        pk.w = (uint32)f2bf_rne(b.z) | ((uint32)f2bf_rne(b.w) << 16);
        *(uint4*)(out + i) = pk;
    }
}

// WT[n][k] = (bf16) W[k][n];  W is [K][N] f32
__global__ __launch_bounds__(256) void wt_kernel(const float* __restrict__ W,
                                                 u16* __restrict__ WT, int K, int N) {
    int idx = blockIdx.x * 256 + threadIdx.x;
    if (idx < K * N) {
        int nrow = idx / K;
        int kcol = idx - nrow * K;
        WT[idx] = f2bf_rne(W[(size_t)kcol * N + nrow]);
    }
}

// ---------------- CSR build ----------------

__global__ void degree_kernel(const int* __restrict__ dst, int* __restrict__ cnt, int n_edges) {
    int i = blockIdx.x * blockDim.x + threadIdx.x;
    if (i < n_edges) atomicAdd(&cnt[dst[i]], 1);
}

__global__ void dinv_kernel(const int* __restrict__ cnt, float* __restrict__ dinv, int n) {
    int i = blockIdx.x * blockDim.x + threadIdx.x;
    if (i < n) dinv[i] = rsqrtf((float)(cnt[i] + 1));
}

__global__ __launch_bounds__(256) void block_sum_kernel(const int* __restrict__ cnt,
                                                        int* __restrict__ bsum, int n) {
    int b = blockIdx.x, t = threadIdx.x;
    int i = b * 256 + t;
    int v = (i < n) ? cnt[i] : 0;
    #pragma unroll
    for (int off = 32; off >= 1; off >>= 1) v += __shfl_down(v, off, 64);
    __shared__ int ws[4];
    if ((t & 63) == 0) ws[t >> 6] = v;
    __syncthreads();
    if (t == 0) bsum[b] = ws[0] + ws[1] + ws[2] + ws[3];
}

__global__ __launch_bounds__(256) void scan_partials_kernel(const int* __restrict__ bsum,
                                                            int* __restrict__ boff,
                                                            int* __restrict__ row_ptr,
                                                            int nb, int n) {
    int t = threadIdx.x;
    int v = (t < nb) ? bsum[t] : 0;
    int lane = t & 63, w = t >> 6;
    int x = v;
    #pragma unroll
    for (int off = 1; off < 64; off <<= 1) {
        int u = __shfl_up(x, off, 64);
        if (lane >= off) x += u;
    }
    __shared__ int ws[4];
    if (lane == 63) ws[w] = x;
    __syncthreads();
    int base = 0;
    for (int i = 0; i < w; ++i) base += ws[i];
    int incl = base + x;
    if (t < nb) boff[t] = incl - v;
    if (t == 255) row_ptr[n] = incl;
}

__global__ __launch_bounds__(256) void scan_write_kernel(const int* __restrict__ cnt,
                                                         const int* __restrict__ boff,
                                                         int* __restrict__ row_ptr,
                                                         int* __restrict__ cursor, int n) {
    int b = blockIdx.x, t = threadIdx.x;
    int i = b * 256 + t;
    int v = (i < n) ? cnt[i] : 0;
    int lane = t & 63, w = t >> 6;
    int x = v;
    #pragma unroll
    for (int off = 1; off < 64; off <<= 1) {
        int u = __shfl_up(x, off, 64);
        if (lane >= off) x += u;
    }
    __shared__ int ws[4];
    if (lane == 63) ws[w] = x;
    __syncthreads();
    int base = boff[b];
    for (int i2 = 0; i2 < w; ++i2) base += ws[i2];
    int excl = base + (x - v);
    if (i < n) { row_ptr[i] = excl; cursor[i] = excl; }
}

__global__ void fill_kernel(const int* __restrict__ src, const int* __restrict__ dst,
                            const float* __restrict__ dinv,
                            int* __restrict__ cursor, int* __restrict__ col,
                            float* __restrict__ ew, int n_edges) {
    int i = blockIdx.x * blockDim.x + threadIdx.x;
    if (i < n_edges) {
        int d = dst[i];
        int s = src[i];
        int pos = atomicAdd(&cursor[d], 1);
        col[pos] = s;
        ew[pos]  = dinv[s] * dinv[d];
    }
}

// ---------------- bf16 MFMA GEMM ----------------
// C[M x NT](bf16) = A[M x 256](bf16) * BT[NT x 256](bf16)^T
// Block: 128 rows x 128 cols, 256 threads = 4 waves in 2x2.
// BK=32 (one mfma_16x16x32 K-step); K=256 -> 8 steps.
// A/B staged via global_load_lds width=16 (contiguous lane order, no pad).

template <int NT>
__global__ __launch_bounds__(256, 4) void gemm_bf16_kernel(const u16* __restrict__ A,
                                                           const u16* __restrict__ BT,
                                                           u16* __restrict__ C, int M) {
    const int K = 256;
    __shared__ short As[128 * 32];   // [m][k] row-major, 64B rows
    __shared__ short Bs[128 * 32];   // [n][k] row-major

    const int m0 = blockIdx.x * 128;
    const int n0 = blockIdx.y * 128;
    const int t  = threadIdx.x;
    const int w  = t >> 6;
    const int lane = t & 63;
    const int lm = lane & 15;        // frag row/col index
    const int lq = lane >> 4;        // quad 0..3
    const int wm = w & 1;            // wave 2x2
    const int wn = w >> 1;

    f32x4 acc[4][4] = {};            // 4 m-tiles x 4 n-tiles of 16x16

    for (int k0 = 0; k0 < K; k0 += 32) {
        // ---- stage A-tile [128][32] and B-tile [128][32] ----
        #pragma unroll
        for (int j = 0; j < 2; ++j) {
            int c = w * 128 + j * 64 + lane;        // chunk id 0..511 (16B each)
            int row = c >> 2;                       // 0..127
            int kc = k0 + (c & 3) * 8;
            int gm = m0 + row; if (gm >= M) gm = M - 1;   // clamp tail (masked at store)
            const u16* gpa = A  + (size_t)gm * K + kc;
            const u16* gpb = BT + (size_t)(n0 + row) * K + kc;
            __builtin_amdgcn_global_load_lds(
                (const __attribute__((address_space(1))) void*)gpa,
                (__attribute__((address_space(3))) void*)(As + (w * 128 + j * 64) * 8),
                16, 0, 0);
            __builtin_amdgcn_global_load_lds(
                (const __attribute__((address_space(1))) void*)gpb,
                (__attribute__((address_space(3))) void*)(Bs + (w * 128 + j * 64) * 8),
                16, 0, 0);
        }
        __syncthreads();

        // ---- frags + MFMA ----
        bf16x8 af[4], bf[4];
        #pragma unroll
        for (int mt = 0; mt < 4; ++mt)
            af[mt] = *(const bf16x8*)&As[(wm * 64 + mt * 16 + lm) * 32 + lq * 8];
        #pragma unroll
        for (int nt = 0; nt < 4; ++nt)
            bf[nt] = *(const bf16x8*)&Bs[(wn * 64 + nt * 16 + lm) * 32 + lq * 8];

        #pragma unroll
        for (int mt = 0; mt < 4; ++mt)
            #pragma unroll
            for (int nt = 0; nt < 4; ++nt)
                acc[mt][nt] = __builtin_amdgcn_mfma_f32_16x16x32_bf16(
                    af[mt], bf[nt], acc[mt][nt], 0, 0, 0);

        __syncthreads();
    }

    // ---- epilogue: C/D layout col=lane&15, row=lq*4+r ----
    #pragma unroll
    for (int mt = 0; mt < 4; ++mt) {
        #pragma unroll
        for (int r = 0; r < 4; ++r) {
            int gm = m0 + wm * 64 + mt * 16 + lq * 4 + r;
            if (gm < M) {
                #pragma unroll
                for (int nt = 0; nt < 4; ++nt) {
                    int gn = n0 + wn * 64 + nt * 16 + lm;
                    C[(size_t)gm * NT + gn] = f2bf_rne(acc[mt][nt][r]);
                }
            }
        }
    }
}

// ---------------- Aggregation: one wave per node, bf16 gather over CSR ----------------

template <int D, bool RELU, bool OUTBF>
__global__ __launch_bounds__(256) void aggregate_kernel(const u16* __restrict__ x,
                                                        const int* __restrict__ row_ptr,
                                                        const int* __restrict__ col,
                                                        const float* __restrict__ ew,
                                                        const float* __restrict__ dinv,
                                                        const float* __restrict__ bias,
                                                        void* __restrict__ outp, int n_nodes) {
    constexpr int VPL = D / 64;   // bf16s per lane: 4 (D=256) or 2 (D=128)
    int wave = (blockIdx.x * blockDim.x + threadIdx.x) >> 6;
    int lane = threadIdx.x & 63;
    if (wave >= n_nodes) return;
    const int node = wave;
    const int c0 = lane * VPL;

    float di = dinv[node];
    float acc[4][VPL] = {};

    {   // self-loop: x[node] * dinv^2
        float w = di * di;
        const u16* xs = x + (size_t)node * D + c0;
        if constexpr (VPL == 4) {
            uint2 p = *(const uint2*)xs;
            acc[0][0] = bf_lo(p.x) * w;
            acc[0][1] = bf_hi(p.x) * w;
            acc[0][2] = bf_lo(p.y) * w;
            acc[0][3] = bf_hi(p.y) * w;
        } else {
            uint32 p = *(const uint32*)xs;
            acc[0][0] = bf_lo(p) * w;
            acc[0][1] = bf_hi(p) * w;
        }
    }

    int e0 = row_ptr[node], e1 = row_ptr[node + 1];
    int e = e0;
    for (; e + 4 <= e1; e += 4) {
        #pragma unroll
        for (int u = 0; u < 4; ++u) {
            int s  = col[e + u];
            float w = ew[e + u];
            const u16* xs = x + (size_t)s * D + c0;
            if constexpr (VPL == 4) {
                uint2 p = *(const uint2*)xs;
                acc[u][0] = fmaf(bf_lo(p.x), w, acc[u][0]);
                acc[u][1] = fmaf(bf_hi(p.x), w, acc[u][1]);
                acc[u][2] = fmaf(bf_lo(p.y), w, acc[u][2]);
                acc[u][3] = fmaf(bf_hi(p.y), w, acc[u][3]);
            } else {
                uint32 p = *(const uint32*)xs;
                acc[u][0] = fmaf(bf_lo(p), w, acc[u][0]);
                acc[u][1] = fmaf(bf_hi(p), w, acc[u][1]);
            }
        }
    }
    for (; e < e1; ++e) {
        int s  = col[e];
        float w = ew[e];
        const u16* xs = x + (size_t)s * D + c0;
        if constexpr (VPL == 4) {
            uint2 p = *(const uint2*)xs;
            acc[0][0] = fmaf(bf_lo(p.x), w, acc[0][0]);
            acc[0][1] = fmaf(bf_hi(p.x), w, acc[0][1]);
            acc[0][2] = fmaf(bf_lo(p.y), w, acc[0][2]);
            acc[0][3] = fmaf(bf_hi(p.y), w, acc[0][3]);
        } else {
            uint32 p = *(const uint32*)xs;
            acc[0][0] = fmaf(bf_lo(p), w, acc[0][0]);
            acc[0][1] = fmaf(bf_hi(p), w, acc[0][1]);
        }
    }

    float v[VPL];
    #pragma unroll
    for (int j = 0; j < VPL; ++j) {
        float s = acc[0][j] + acc[1][j] + acc[2][j] + acc[3][j] + bias[c0 + j];
        v[j] = RELU ? fmaxf(s, 0.0f) : s;
    }

    if constexpr (OUTBF) {
        u16* op = (u16*)outp + (size_t)node * D + c0;
        if constexpr (VPL == 4) {
            uint2 pk;
            pk.x = (uint32)f2bf_rne(v[0]) | ((uint32)f2bf_rne(v[1]) << 16);
            pk.y = (uint32)f2bf_rne(v[2]) | ((uint32)f2bf_rne(v[3]) << 16);
            *(uint2*)op = pk;
        } else {
            *(uint32*)op = (uint32)f2bf_rne(v[0]) | ((uint32)f2bf_rne(v[1]) << 16);
        }
    } else {
        float* op = (float*)outp + (size_t)node * D + c0;
        #pragma unroll
        for (int j = 0; j < VPL; ++j) op[j] = v[j];
    }
}

// ---------------- launcher ----------------

extern "C" void kernel_launch(void* const* d_in, const int* in_sizes, int n_in,
                              void* d_out, int out_size, void* d_ws, size_t ws_size,
                              hipStream_t stream) {
    const float* z  = (const float*)d_in[0];
    const int*   ei = (const int*)d_in[1];
    const float* W1 = (const float*)d_in[2];
    const float* b1 = (const float*)d_in[3];
    const float* W2 = (const float*)d_in[4];
    const float* b2 = (const float*)d_in[5];
    float* out = (float*)d_out;

    const int Nn = N_NODES, E = N_EDGES;
    const int* srcp = ei;
    const int* dstp = ei + E;

    char* ws = (char*)d_ws;
    size_t off = 0;
    auto alloc = [&](size_t bytes) -> char* {
        char* p = ws + off;
        off += (bytes + 511) & ~(size_t)511;
        return p;
    };
    u16*   zb     = (u16*)  alloc((size_t)Nn * D_IN * 2);    // z bf16
    u16*   w1t    = (u16*)  alloc((size_t)D_IN * D_HID * 2); // W1^T bf16 [N][K]
    u16*   w2t    = (u16*)  alloc((size_t)D_HID * D_OUT * 2);// W2^T bf16 [N][K]
    u16*   x1b    = (u16*)  alloc((size_t)Nn * D_HID * 2);   // z @ W1, bf16
    u16*   hb     = (u16*)  alloc((size_t)Nn * D_HID * 2);   // relu(agg+b1), bf16
    u16*   h2b    = (u16*)  alloc((size_t)Nn * D_OUT * 2);   // h @ W2, bf16
    int*   cnt    = (int*)  alloc((size_t)Nn * 4);
    float* dinv   = (float*)alloc((size_t)Nn * 4);
    int*   row_ptr= (int*)  alloc((size_t)(Nn + 1) * 4);
    int*   cursor = (int*)  alloc((size_t)Nn * 4);
    int*   col    = (int*)  alloc((size_t)E * 4);
    float* ew     = (float*)alloc((size_t)E * 4);
    int*   bsum   = (int*)  alloc(256 * 4);
    int*   boff   = (int*)  alloc(256 * 4);

    const int nb = (Nn + 255) / 256;

    // ---- conversions ----
    cvt_bf16_kernel<<<(Nn * D_IN / 8 + 255) / 256, 256, 0, stream>>>(z, zb, Nn * D_IN);
    wt_kernel<<<(D_IN * D_HID + 255) / 256, 256, 0, stream>>>(W1, w1t, D_IN, D_HID);
    wt_kernel<<<(D_HID * D_OUT + 255) / 256, 256, 0, stream>>>(W2, w2t, D_HID, D_OUT);

    // ---- CSR build ----
    hipMemsetAsync(cnt, 0, (size_t)Nn * 4, stream);
    degree_kernel<<<(E + 255) / 256, 256, 0, stream>>>(dstp, cnt, E);
    dinv_kernel<<<(Nn + 255) / 256, 256, 0, stream>>>(cnt, dinv, Nn);
    block_sum_kernel<<<nb, 256, 0, stream>>>(cnt, bsum, Nn);
    scan_partials_kernel<<<1, 256, 0, stream>>>(bsum, boff, row_ptr, nb, Nn);
    scan_write_kernel<<<nb, 256, 0, stream>>>(cnt, boff, row_ptr, cursor, Nn);
    fill_kernel<<<(E + 255) / 256, 256, 0, stream>>>(srcp, dstp, dinv, cursor, col, ew, E);

    // ---- layer 1 ----
    {
        dim3 grid((Nn + 127) / 128, D_HID / 128);
        gemm_bf16_kernel<D_HID><<<grid, 256, 0, stream>>>(zb, w1t, x1b, Nn);
    }
    {
        int blocks = (Nn * 64 + 255) / 256;
        aggregate_kernel<D_HID, true, true><<<blocks, 256, 0, stream>>>(x1b, row_ptr, col, ew, dinv, b1, hb, Nn);
    }

    // ---- layer 2 ----
    {
        dim3 grid((Nn + 127) / 128, D_OUT / 128);
        gemm_bf16_kernel<D_OUT><<<grid, 256, 0, stream>>>(hb, w2t, h2b, Nn);
    }
    {
        int blocks = (Nn * 64 + 255) / 256;
        aggregate_kernel<D_OUT, false, false><<<blocks, 256, 0, stream>>>(h2b, row_ptr, col, ew, dinv, b2, out, Nn);
    }
}